// Round 4
// baseline (24586.600 us; speedup 1.0000x reference)
//
#include <hip/hip_runtime.h>

// 2-layer tanh RNN, B=32, T=1024, H=1024.
// Round 4: per-wave full-K pipeline + prelude GEMM for the layer-0 input
// projection. Sync semantics reverted to the PROVEN R1 scheme:
//   producer: write-through agent atomic data stores -> RELEASE flag store
//             (vmcnt drain + wbl2 emitted by the release)
//   consumer: lane-parallel spin on per-producer-wave flags -> acquire fence
//             (buffer_inv) -> plain loads
// Structure:
//   prep   : zero rings + flags
//   xgemm  : xp = x @ Wx0^T + bx0+bh0  -> written into `out` (scratch reuse;
//            out[:,t,:] is rewritten by rec-l1[t] only after all rec-l0[t]
//            waves consumed xp[:,t,:] -- guaranteed by the pj1 dep chain)
//   rnn_pipe (96 WGs):
//     wg  0..31: rec layer0   (2 bg x 16): wave = 16 cols x full K, Wh0 in VGPR
//     wg 32..63: rec layer1   : same with Wh1; reads pj1 ring, writes out
//     wg 64..95: proj1        : pj1 = h0[t] @ Wx1^T + b1, Wx1 in VGPR
//   No LDS, no __syncthreads in the pipeline: each wave is an independent
//   producer with its own flag; consumers poll 64 flags lane-parallel.
#define BB 32
#define TT 1024
#define HH 1024
#define NR 32     // ring0 depth (h0)
#define NP1 8     // pj1 ring depth

typedef float f32x4 __attribute__((ext_vector_type(4)));
typedef short bf16x8 __attribute__((ext_vector_type(8)));
typedef unsigned uint4v __attribute__((ext_vector_type(4)));
typedef unsigned short u16;

__device__ __forceinline__ u16 f2bf(float f) {
  unsigned u = __builtin_bit_cast(unsigned, f);
  u += 0x7fffu + ((u >> 16) & 1u);   // RNE
  return (u16)(u >> 16);
}
__device__ __forceinline__ float bf2f(u16 h) {
  return __builtin_bit_cast(float, (unsigned)h << 16);
}
__device__ __forceinline__ bf16x8 packhi(f32x4 a, f32x4 b) {
  bf16x8 r;
  r[0] = (short)f2bf(a[0]); r[1] = (short)f2bf(a[1]);
  r[2] = (short)f2bf(a[2]); r[3] = (short)f2bf(a[3]);
  r[4] = (short)f2bf(b[0]); r[5] = (short)f2bf(b[1]);
  r[6] = (short)f2bf(b[2]); r[7] = (short)f2bf(b[3]);
  return r;
}
__device__ __forceinline__ bf16x8 packlo(f32x4 a, f32x4 b, bf16x8 hi) {
  bf16x8 r;
  r[0] = (short)f2bf(a[0] - bf2f((u16)hi[0]));
  r[1] = (short)f2bf(a[1] - bf2f((u16)hi[1]));
  r[2] = (short)f2bf(a[2] - bf2f((u16)hi[2]));
  r[3] = (short)f2bf(a[3] - bf2f((u16)hi[3]));
  r[4] = (short)f2bf(b[0] - bf2f((u16)hi[4]));
  r[5] = (short)f2bf(b[1] - bf2f((u16)hi[5]));
  r[6] = (short)f2bf(b[2] - bf2f((u16)hi[6]));
  r[7] = (short)f2bf(b[3] - bf2f((u16)hi[7]));
  return r;
}
__device__ __forceinline__ bf16x8 mergelo(uint4v q0, uint4v q1) {  // hi-bf16 plane
  uint4v r;
  r.x = __builtin_amdgcn_perm(q0.y, q0.x, 0x05040100u);
  r.y = __builtin_amdgcn_perm(q0.w, q0.z, 0x05040100u);
  r.z = __builtin_amdgcn_perm(q1.y, q1.x, 0x05040100u);
  r.w = __builtin_amdgcn_perm(q1.w, q1.z, 0x05040100u);
  return __builtin_bit_cast(bf16x8, r);
}
__device__ __forceinline__ bf16x8 mergehi(uint4v q0, uint4v q1) {  // lo-bf16 plane
  uint4v r;
  r.x = __builtin_amdgcn_perm(q0.y, q0.x, 0x07060302u);
  r.y = __builtin_amdgcn_perm(q0.w, q0.z, 0x07060302u);
  r.z = __builtin_amdgcn_perm(q1.y, q1.x, 0x07060302u);
  r.w = __builtin_amdgcn_perm(q1.w, q1.z, 0x07060302u);
  return __builtin_bit_cast(bf16x8, r);
}
__device__ __forceinline__ void spin(const unsigned* p, unsigned tgt) {
  while (__hip_atomic_load(p, __ATOMIC_RELAXED, __HIP_MEMORY_SCOPE_AGENT) < tgt)
    __builtin_amdgcn_s_sleep(1);
}
#define MFMA __builtin_amdgcn_mfma_f32_16x16x32_bf16

// ---------------- prelude GEMM: xp = x @ Wx0^T + (bx0+bh0) ----------------
// M = B*T = 32768 rows, N = 1024, K = 1024. Output into xp[m*HH + n] (= out).
__global__ __launch_bounds__(256, 2) void xgemm(
    const float* __restrict__ x, const float* __restrict__ Wx,
    const float* __restrict__ bx, const float* __restrict__ bh,
    float* __restrict__ xp)
{
  __shared__ float red[4][16 * 68];
  const int tid   = threadIdx.x;
  const int strip = blockIdx.x & 15;
  const int chunk = blockIdx.x >> 4;   // 0..31
  const int n0    = strip << 6;
  const int m0    = chunk << 10;       // 1024 rows per chunk
  const int lane  = tid & 63;
  const int wv    = tid >> 6;
  const int am    = lane & 15;
  const int aq    = lane >> 4;
  const int fragoff = (wv << 8) + (aq << 3);
  const int rowE = tid >> 4;
  const int cb   = tid & 15;

  bf16x8 wHi[4][8], wLo[4][8];
  #pragma unroll
  for (int j = 0; j < 4; ++j) {
    const float* p = Wx + (size_t)(n0 + (j << 4) + am) * HH + fragoff;
    #pragma unroll
    for (int ss = 0; ss < 8; ++ss) {
      f32x4 a = *(const f32x4*)(p + (ss << 5));
      f32x4 b = *(const f32x4*)(p + (ss << 5) + 4);
      wHi[j][ss] = packhi(a, b);
      wLo[j][ss] = packlo(a, b, wHi[j][ss]);
    }
  }
  float bias[4];
  #pragma unroll
  for (int k = 0; k < 4; ++k)
    bias[k] = bx[n0 + cb + (k << 4)] + bh[n0 + cb + (k << 4)];
  const f32x4 z4 = {0.f, 0.f, 0.f, 0.f};

  for (int it = 0; it < 64; ++it) {
    const int r0 = m0 + (it << 4);
    const float* xr = x + (size_t)(r0 + am) * HH + fragoff;
    f32x4 accA[4] = {z4, z4, z4, z4};
    f32x4 accB[4] = {z4, z4, z4, z4};
    f32x4 accC[4] = {z4, z4, z4, z4};
    #pragma unroll
    for (int ss = 0; ss < 8; ++ss) {
      f32x4 a = *(const f32x4*)(xr + (ss << 5));
      f32x4 b = *(const f32x4*)(xr + (ss << 5) + 4);
      bf16x8 xh = packhi(a, b);
      bf16x8 xl = packlo(a, b, xh);
      #pragma unroll
      for (int j = 0; j < 4; ++j) {
        accA[j] = MFMA(xh, wHi[j][ss], accA[j], 0, 0, 0);
        accB[j] = MFMA(xh, wLo[j][ss], accB[j], 0, 0, 0);
        accC[j] = MFMA(xl, wHi[j][ss], accC[j], 0, 0, 0);
      }
    }
    #pragma unroll
    for (int j = 0; j < 4; ++j) {
      f32x4 s = (accA[j] + accB[j]) + accC[j];
      #pragma unroll
      for (int i = 0; i < 4; ++i)
        red[wv][((aq << 2) + i) * 68 + (j << 4) + am] = s[i];
    }
    __syncthreads();
    #pragma unroll
    for (int k = 0; k < 4; ++k) {
      const int c = cb + (k << 4);
      float v = red[0][rowE * 68 + c] + red[1][rowE * 68 + c]
              + red[2][rowE * 68 + c] + red[3][rowE * 68 + c] + bias[k];
      xp[(size_t)(r0 + rowE) * HH + n0 + c] = v;
    }
    __syncthreads();   // red reused next iteration
  }
}

// ---------------- persistent pipeline ----------------
// flag groups: 0,1 = rec-l0(bg) ; 2,3 = rec-l1(bg) ; 4,5 = proj1(bg)
__global__ __launch_bounds__(256, 1) void rnn_pipe(
    const float* __restrict__ Wx, const float* __restrict__ Wh,
    const float* __restrict__ bx, const float* __restrict__ bh,
    float* __restrict__ out,       // [B,T,H] (= xp scratch) + h_n tail
    unsigned* __restrict__ ring0,  // [NR][BB][HH] u32 (hi|lo<<16)
    unsigned* __restrict__ h1r,    // [2][BB][HH] u32
    float* __restrict__ pj1,       // [NP1][BB][HH] f32
    unsigned* __restrict__ flg)    // [6][TT][64]
{
  const int tid  = threadIdx.x;
  const int wg   = blockIdx.x;
  const int role = wg >> 5;        // 0 rec-l0, 1 rec-l1, 2 proj1
  const int bg   = (wg >> 4) & 1;
  const int idx  = wg & 15;
  const int lane = tid & 63;
  const int wv   = tid >> 6;
  const int am   = lane & 15;
  const int aq   = lane >> 4;
  const int p    = (idx << 2) | wv;   // producer-wave id 0..63
  const int wcb  = p << 4;            // this wave's 16-col base
  const int b0   = bg << 4;
  const int row0 = aq << 2;           // epilogue rows row0..row0+3, col = am

  // ---- one-time: 16 cols x full K weights into VGPRs (hi/lo) ----
  const float* WM = (role == 0) ? Wh
                  : (role == 1) ? Wh + (size_t)HH * HH
                                : Wx + (size_t)HH * HH;
  bf16x8 wHi[32], wLo[32];
  {
    const float* wp = WM + (size_t)(wcb + am) * HH + (aq << 3);
    #pragma unroll
    for (int ss = 0; ss < 32; ++ss) {
      f32x4 a = *(const f32x4*)(wp + (ss << 5));
      f32x4 b = *(const f32x4*)(wp + (ss << 5) + 4);
      wHi[ss] = packhi(a, b);
      wLo[ss] = packlo(a, b, wHi[ss]);
    }
  }
  const f32x4 z4 = {0.f, 0.f, 0.f, 0.f};

  if (role < 2) {
    // ========================= recurrent wave =========================
    const int gOwn = role * 2 + bg;
    for (int t = 0; t < TT; ++t) {
      // lane-parallel poll: lane L waits producer-wave L of own group, t-1
      if (t >= 1) spin(flg + (((size_t)gOwn * TT + (t - 1)) << 6) + lane, 1);
      if (role == 0) {
        // ring0 backpressure vs proj1, amortized over 8 steps
        if ((t & 7) == 0 && t >= NR)
          spin(flg + (((size_t)(4 + bg) * TT + (t - 25)) << 6) + lane, 1);
      } else {
        // pj1 tile for this wave's cols, produced by proj1 wave p
        if (lane == 0)
          spin(flg + (((size_t)(4 + bg) * TT + t) << 6) + p, 1);
      }
      __builtin_amdgcn_fence(__ATOMIC_ACQUIRE, "agent");

      // projection tile (f32): rec-l0 from xp(=out), rec-l1 from pj1 ring
      float pjv[4];
      if (role == 0) {
        const float* q = out + ((size_t)(b0 + row0) * TT + t) * HH + wcb + am;
        #pragma unroll
        for (int i = 0; i < 4; ++i) pjv[i] = q[(size_t)i * TT * HH];
      } else {
        const float* q = pj1 + (size_t)(t & (NP1 - 1)) * (BB * HH)
                       + (b0 + row0) * HH + wcb + am;
        #pragma unroll
        for (int i = 0; i < 4; ++i) pjv[i] = q[i * HH];
      }

      const unsigned* hp = (role == 0
            ? ring0 + (size_t)((t - 1) & (NR - 1)) * (BB * HH)
            : h1r  + (size_t)((t - 1) & 1) * (BB * HH))
          + (b0 + am) * HH + (aq << 3);

      f32x4 aA = z4, aB = z4, aC = z4;
      #pragma unroll
      for (int ss = 0; ss < 32; ++ss) {
        uint4v q0 = *(const uint4v*)(hp + (ss << 5));
        uint4v q1 = *(const uint4v*)(hp + (ss << 5) + 4);
        bf16x8 aH = mergelo(q0, q1);
        bf16x8 aL = mergehi(q0, q1);
        aA = MFMA(aH, wHi[ss], aA, 0, 0, 0);
        aB = MFMA(aH, wLo[ss], aB, 0, 0, 0);
        aC = MFMA(aL, wHi[ss], aC, 0, 0, 0);
      }
      f32x4 acc = (aA + aB) + aC;

      float hv[4]; unsigned pk[4];
      #pragma unroll
      for (int i = 0; i < 4; ++i) {
        float v = acc[i] + pjv[i];
        hv[i] = tanhf(v);
        unsigned pw = (unsigned)f2bf(hv[i]);
        pw |= (unsigned)f2bf(hv[i] - bf2f((u16)pw)) << 16;
        pk[i] = pw;
      }
      unsigned* dst = (role == 0
            ? ring0 + (size_t)(t & (NR - 1)) * (BB * HH)
            : h1r  + (size_t)(t & 1) * (BB * HH))
          + (b0 + row0) * HH + wcb + am;
      #pragma unroll
      for (int i = 0; i < 4; ++i)
        __hip_atomic_store(dst + i * HH, pk[i],
                           __ATOMIC_RELAXED, __HIP_MEMORY_SCOPE_AGENT);
      if (lane == 0)
        __hip_atomic_store(flg + (((size_t)gOwn * TT + t) << 6) + p, 1u,
                           __ATOMIC_RELEASE, __HIP_MEMORY_SCOPE_AGENT);

      // off-critical-path: outputs (NT keeps L2 clean for the wbl2 in RELEASE)
      if (role == 1) {
        float* ob = out + (size_t)(b0 + row0) * (TT * HH) + (size_t)t * HH + wcb + am;
        #pragma unroll
        for (int i = 0; i < 4; ++i)
          __builtin_nontemporal_store(hv[i], ob + (size_t)i * TT * HH);
      }
      if (t == TT - 1) {
        float* hb = out + (size_t)BB * TT * HH + (size_t)role * (BB * HH)
                  + (b0 + row0) * HH + wcb + am;
        #pragma unroll
        for (int i = 0; i < 4; ++i)
          __builtin_nontemporal_store(hv[i], hb + i * HH);
      }
    }
  } else {
    // ========================= proj1 wave: pj1 = h0[t] @ Wx1^T + b1 =========
    const float biasv = bx[HH + wcb + am] + bh[HH + wcb + am];
    for (int t = 0; t < TT; ++t) {
      spin(flg + (((size_t)bg * TT + t) << 6) + lane, 1);      // rec-l0 flags t
      if ((t & 3) == 0 && t >= NP1)                            // pj1 ring BP
        spin(flg + (((size_t)(2 + bg) * TT + (t - 5)) << 6) + lane, 1);
      __builtin_amdgcn_fence(__ATOMIC_ACQUIRE, "agent");

      const unsigned* hp = ring0 + (size_t)(t & (NR - 1)) * (BB * HH)
                         + (b0 + am) * HH + (aq << 3);
      f32x4 aA = z4, aB = z4, aC = z4;
      #pragma unroll
      for (int ss = 0; ss < 32; ++ss) {
        uint4v q0 = *(const uint4v*)(hp + (ss << 5));
        uint4v q1 = *(const uint4v*)(hp + (ss << 5) + 4);
        bf16x8 aH = mergelo(q0, q1);
        bf16x8 aL = mergehi(q0, q1);
        aA = MFMA(aH, wHi[ss], aA, 0, 0, 0);
        aB = MFMA(aH, wLo[ss], aB, 0, 0, 0);
        aC = MFMA(aL, wHi[ss], aC, 0, 0, 0);
      }
      f32x4 acc = (aA + aB) + aC;

      float* dst = pj1 + (size_t)(t & (NP1 - 1)) * (BB * HH)
                 + (b0 + row0) * HH + wcb + am;
      #pragma unroll
      for (int i = 0; i < 4; ++i)
        __hip_atomic_store((unsigned*)(dst + i * HH),
                           __builtin_bit_cast(unsigned, acc[i] + biasv),
                           __ATOMIC_RELAXED, __HIP_MEMORY_SCOPE_AGENT);
      if (lane == 0)
        __hip_atomic_store(flg + (((size_t)(4 + bg) * TT + t) << 6) + p, 1u,
                           __ATOMIC_RELEASE, __HIP_MEMORY_SCOPE_AGENT);
    }
  }
}

// Zero what is read before first write (harness poisons ws with 0xAA):
// ring0 slot NR-1 (h0_{-1}=0), h1r slot 1 (h1_{-1}=0), all flags.
__global__ void prep(unsigned* ring0, unsigned* h1r, unsigned* flg) {
  int i = blockIdx.x * 256 + threadIdx.x;
  if (i < BB * HH) {
    ring0[(size_t)(NR - 1) * (BB * HH) + i] = 0;
    h1r[(size_t)(BB * HH) + i] = 0;
  }
  if (i < 6 * TT * 64) flg[i] = 0;
}

extern "C" void kernel_launch(void* const* d_in, const int* in_sizes, int n_in,
                              void* d_out, int out_size, void* d_ws, size_t ws_size,
                              hipStream_t stream) {
  const float* x  = (const float*)d_in[0];
  const float* Wx = (const float*)d_in[1];
  const float* Wh = (const float*)d_in[2];
  const float* bx = (const float*)d_in[3];
  const float* bh = (const float*)d_in[4];
  float* out = (float*)d_out;

  char* ws = (char*)d_ws;
  unsigned* ring0 = (unsigned*)ws;                                   // 4 MiB
  size_t o = (size_t)NR * BB * HH * sizeof(unsigned);
  unsigned* h1r = (unsigned*)(ws + o);                               // 256 KiB
  o += (size_t)2 * BB * HH * sizeof(unsigned);
  float* pj1 = (float*)(ws + o);                                     // 1 MiB
  o += (size_t)NP1 * BB * HH * sizeof(float);
  unsigned* flg = (unsigned*)(ws + o);                               // 1.5 MiB
  // total ~6.8 MiB

  prep<<<1536, 256, 0, stream>>>(ring0, h1r, flg);
  // prelude: xp = x @ Wx0^T + b  -> out (scratch; rewritten by rec-l1 later)
  xgemm<<<512, 256, 0, stream>>>(x, Wx, bx, bh, out);
  rnn_pipe<<<96, 256, 0, stream>>>(Wx, Wh, bx, bh, out,
                                   ring0, h1r, pj1, flg);
}

// Round 5
// 9829.611 us; speedup vs baseline: 2.5013x; 2.5013x over previous
//
#include <hip/hip_runtime.h>

// 2-layer tanh RNN, B=32, T=1024, H=1024.
// Round 5: R1 squad structure (proven sync), weights made ACTUALLY resident.
// Discovery: R1/R4 VGPR_Count (192/164) < declared weight regs (256+) => the
// compiler was spilling/reloading weight fragments EVERY STEP, from
// L2-invalidated memory (the per-step acquire fence nukes L2) => ~16KB/wave
// MALL reads per step on the critical path.
// Fix: 512-thread WGs, K split across 8 waves -> 32 bf16x8 = 128 VGPRs of
// weights per wave, total ~220 regs, enforced by __launch_bounds__(512,2).
//   prep  : zero rings/flags, set `ones`
//   xgemm : xp = x @ Wx0^T + bx0+bh0 -> out (scratch; safe, see R4 audit)
//   rnn_pipe (96 WGs x 512 thr): role 0 = rec-l0 (16 WG x 2bg),
//     role 1 = rec-l1, role 2 = proj1 (pj1 = h0[t] @ Wx1^T + b1).
// Sync (PROVEN R1 scheme): producer write-through agent-atomic data stores ->
// __syncthreads (vmcnt drain) -> tid0 RELEASE flag; consumer: one fused
// wave-wide spin (idle lanes watch `ones`) -> acquire fence -> plain loads.
#define BB 32
#define TT 1024
#define HH 1024
#define NR 32     // ring0 depth (h0)
#define NP1 8     // pj1 ring depth

typedef float f32x4 __attribute__((ext_vector_type(4)));
typedef short bf16x8 __attribute__((ext_vector_type(8)));
typedef unsigned uint4v __attribute__((ext_vector_type(4)));
typedef unsigned short u16;

__device__ __forceinline__ u16 f2bf(float f) {
  unsigned u = __builtin_bit_cast(unsigned, f);
  u += 0x7fffu + ((u >> 16) & 1u);   // RNE
  return (u16)(u >> 16);
}
__device__ __forceinline__ float bf2f(u16 h) {
  return __builtin_bit_cast(float, (unsigned)h << 16);
}
__device__ __forceinline__ bf16x8 packhi(f32x4 a, f32x4 b) {
  bf16x8 r;
  r[0] = (short)f2bf(a[0]); r[1] = (short)f2bf(a[1]);
  r[2] = (short)f2bf(a[2]); r[3] = (short)f2bf(a[3]);
  r[4] = (short)f2bf(b[0]); r[5] = (short)f2bf(b[1]);
  r[6] = (short)f2bf(b[2]); r[7] = (short)f2bf(b[3]);
  return r;
}
__device__ __forceinline__ bf16x8 packlo(f32x4 a, f32x4 b, bf16x8 hi) {
  bf16x8 r;
  r[0] = (short)f2bf(a[0] - bf2f((u16)hi[0]));
  r[1] = (short)f2bf(a[1] - bf2f((u16)hi[1]));
  r[2] = (short)f2bf(a[2] - bf2f((u16)hi[2]));
  r[3] = (short)f2bf(a[3] - bf2f((u16)hi[3]));
  r[4] = (short)f2bf(b[0] - bf2f((u16)hi[4]));
  r[5] = (short)f2bf(b[1] - bf2f((u16)hi[5]));
  r[6] = (short)f2bf(b[2] - bf2f((u16)hi[6]));
  r[7] = (short)f2bf(b[3] - bf2f((u16)hi[7]));
  return r;
}
__device__ __forceinline__ bf16x8 mergelo(uint4v q0, uint4v q1) {  // hi plane
  uint4v r;
  r.x = __builtin_amdgcn_perm(q0.y, q0.x, 0x05040100u);
  r.y = __builtin_amdgcn_perm(q0.w, q0.z, 0x05040100u);
  r.z = __builtin_amdgcn_perm(q1.y, q1.x, 0x05040100u);
  r.w = __builtin_amdgcn_perm(q1.w, q1.z, 0x05040100u);
  return __builtin_bit_cast(bf16x8, r);
}
__device__ __forceinline__ bf16x8 mergehi(uint4v q0, uint4v q1) {  // lo plane
  uint4v r;
  r.x = __builtin_amdgcn_perm(q0.y, q0.x, 0x07060302u);
  r.y = __builtin_amdgcn_perm(q0.w, q0.z, 0x07060302u);
  r.z = __builtin_amdgcn_perm(q1.y, q1.x, 0x07060302u);
  r.w = __builtin_amdgcn_perm(q1.w, q1.z, 0x07060302u);
  return __builtin_bit_cast(bf16x8, r);
}
__device__ __forceinline__ void spin(const unsigned* p, unsigned tgt) {
  while (__hip_atomic_load(p, __ATOMIC_RELAXED, __HIP_MEMORY_SCOPE_AGENT) < tgt)
    __builtin_amdgcn_s_sleep(1);
}
// fast tanh: clamp + native exp + rcp; |err| ~1e-6, well under the 2^-8 floor
__device__ __forceinline__ float ftanh(float v) {
  float c = fminf(fmaxf(v, -9.5f), 9.5f);
  float e = __expf(2.0f * c);
  return (e - 1.0f) * __builtin_amdgcn_rcpf(e + 1.0f);
}
#define MFMA __builtin_amdgcn_mfma_f32_16x16x32_bf16

// ---------------- prelude GEMM: xp = x @ Wx0^T + (bx0+bh0) ----------------
// M = 32768, N = 1024, K = 1024. 1024 WGs x 512 thr; 8-wave K-split so the
// 32 bf16x8 weight fragments stay register-resident.
__global__ __launch_bounds__(512, 2) void xgemm(
    const float* __restrict__ x, const float* __restrict__ Wx,
    const float* __restrict__ bx, const float* __restrict__ bh,
    float* __restrict__ xp)
{
  __shared__ float red[8][16 * 68];
  const int tid   = threadIdx.x;
  const int strip = blockIdx.x & 15;
  const int chunk = blockIdx.x >> 4;   // 0..63
  const int n0    = strip << 6;
  const int m0    = chunk << 9;        // 512 rows per chunk
  const int lane  = tid & 63;
  const int wv    = tid >> 6;          // 0..7 = K-eighth
  const int am    = lane & 15;
  const int aq    = lane >> 4;
  const int fragoff = (wv << 7) + (aq << 3);
  const int rowE = tid >> 5;           // 0..15
  const int c0   = tid & 31;

  bf16x8 wHi[4][4], wLo[4][4];
  #pragma unroll
  for (int j = 0; j < 4; ++j) {
    const float* wp = Wx + (size_t)(n0 + (j << 4) + am) * HH + fragoff;
    #pragma unroll
    for (int ss = 0; ss < 4; ++ss) {
      f32x4 a = *(const f32x4*)(wp + (ss << 5));
      f32x4 b = *(const f32x4*)(wp + (ss << 5) + 4);
      wHi[j][ss] = packhi(a, b);
      wLo[j][ss] = packlo(a, b, wHi[j][ss]);
    }
  }
  float bias[2];
  bias[0] = bx[n0 + c0] + bh[n0 + c0];
  bias[1] = bx[n0 + c0 + 32] + bh[n0 + c0 + 32];
  const f32x4 z4 = {0.f, 0.f, 0.f, 0.f};

  for (int it = 0; it < 32; ++it) {
    const int r0 = m0 + (it << 4);
    const float* xr = x + (size_t)(r0 + am) * HH + fragoff;
    f32x4 accA[4] = {z4, z4, z4, z4};
    f32x4 accB[4] = {z4, z4, z4, z4};
    f32x4 accC[4] = {z4, z4, z4, z4};
    #pragma unroll
    for (int ss = 0; ss < 4; ++ss) {
      f32x4 a = *(const f32x4*)(xr + (ss << 5));
      f32x4 b = *(const f32x4*)(xr + (ss << 5) + 4);
      bf16x8 xh = packhi(a, b);
      bf16x8 xl = packlo(a, b, xh);
      #pragma unroll
      for (int j = 0; j < 4; ++j) {
        accA[j] = MFMA(xh, wHi[j][ss], accA[j], 0, 0, 0);
        accB[j] = MFMA(xh, wLo[j][ss], accB[j], 0, 0, 0);
        accC[j] = MFMA(xl, wHi[j][ss], accC[j], 0, 0, 0);
      }
    }
    #pragma unroll
    for (int j = 0; j < 4; ++j) {
      f32x4 s = (accA[j] + accB[j]) + accC[j];
      #pragma unroll
      for (int i = 0; i < 4; ++i)
        red[wv][((aq << 2) + i) * 68 + (j << 4) + am] = s[i];
    }
    __syncthreads();
    #pragma unroll
    for (int k = 0; k < 2; ++k) {
      const int c = c0 + (k << 5);
      float v = bias[k];
      #pragma unroll
      for (int w = 0; w < 8; ++w) v += red[w][rowE * 68 + c];
      xp[(size_t)(r0 + rowE) * HH + n0 + c] = v;
    }
    __syncthreads();
  }
}

// ---------------- persistent pipeline ----------------
// flag groups: 0,1 = rec-l0(bg) ; 2,3 = rec-l1(bg) ; 4,5 = proj1(bg)
__global__ __launch_bounds__(512, 2) void rnn_pipe(
    const float* __restrict__ Wx, const float* __restrict__ Wh,
    const float* __restrict__ bx, const float* __restrict__ bh,
    float* __restrict__ out,       // [B,T,H] (= xp scratch) + h_n tail
    unsigned* __restrict__ ring0,  // [NR][BB][HH] u32 (hi|lo<<16)
    unsigned* __restrict__ h1r,    // [2][BB][HH] u32
    float* __restrict__ pj1,       // [NP1][BB][HH] f32
    unsigned* __restrict__ flg,    // [6][TT][16]
    const unsigned* __restrict__ ones)   // always-1 word for idle poll lanes
{
  __shared__ float red[8][16 * 68];
  const int tid  = threadIdx.x;
  const int wg   = blockIdx.x;
  const int role = wg >> 5;        // 0 rec-l0, 1 rec-l1, 2 proj1
  const int bg   = (wg >> 4) & 1;
  const int idx  = wg & 15;
  const int n0   = idx << 6;       // 64 output cols per WG
  const int b0   = bg << 4;
  const int lane = tid & 63;
  const int wv   = tid >> 6;       // 0..7 = K-eighth (128 K)
  const int am   = lane & 15;
  const int aq   = lane >> 4;
  const int fragoff = (wv << 7) + (aq << 3);
  const int rowE = tid >> 5;       // epilogue row 0..15
  const int c0   = tid & 31;       // epilogue cols c0, c0+32

  // ---- one-time: weights into VGPRs, hi/lo, 4 n-tiles x 4 K-subtiles ----
  const float* WM = (role == 0) ? Wh
                  : (role == 1) ? Wh + (size_t)HH * HH
                                : Wx + (size_t)HH * HH;
  bf16x8 wHi[4][4], wLo[4][4];
  #pragma unroll
  for (int j = 0; j < 4; ++j) {
    const float* wp = WM + (size_t)(n0 + (j << 4) + am) * HH + fragoff;
    #pragma unroll
    for (int ss = 0; ss < 4; ++ss) {
      f32x4 a = *(const f32x4*)(wp + (ss << 5));
      f32x4 b = *(const f32x4*)(wp + (ss << 5) + 4);
      wHi[j][ss] = packhi(a, b);
      wLo[j][ss] = packlo(a, b, wHi[j][ss]);
    }
  }
  const f32x4 z4 = {0.f, 0.f, 0.f, 0.f};

  if (role < 2) {
    // ========================= recurrent squad =========================
    const int gOwn = role * 2 + bg;
    for (int t = 0; t < TT; ++t) {
      // ONE fused wave-wide spin; idle lanes watch `ones`.
      const unsigned* pa = ones;
      if (role == 0) {
        if (lane < 2) {                       // own squad t-1, my K-eighth
          if (t >= 1) pa = flg + (((size_t)gOwn * TT + (t - 1)) << 4) + (wv << 1) + lane;
        } else if (lane == 8 || lane == 9) {  // ring0 overwrite vs proj1
          if (t >= NR) pa = flg + (((size_t)(4 + bg) * TT + (t - NR)) << 4) + (wv << 1) + (lane - 8);
        }
      } else {
        if (lane < 2) {
          if (t >= 1) pa = flg + (((size_t)gOwn * TT + (t - 1)) << 4) + (wv << 1) + lane;
        } else if (lane == 4) {               // pj1 tile for my cols
          pa = flg + (((size_t)(4 + bg) * TT + t) << 4) + idx;
        }
      }
      spin(pa, 1);
      __builtin_amdgcn_fence(__ATOMIC_ACQUIRE, "agent");

      // prefetch projection tile (latency hides under MFMA + reduce)
      float pjv[2];
      {
        const float* q = (role == 0)
            ? out + ((size_t)(b0 + rowE) * TT + t) * HH + n0 + c0
            : pj1 + (size_t)(t & (NP1 - 1)) * (BB * HH) + (b0 + rowE) * HH + n0 + c0;
        pjv[0] = q[0]; pjv[1] = q[32];
      }

      const unsigned* hp = ((role == 0)
            ? ring0 + (size_t)((t - 1) & (NR - 1)) * (BB * HH)
            : h1r  + (size_t)((t - 1) & 1) * (BB * HH))
          + (b0 + am) * HH + fragoff;

      f32x4 accA[4] = {z4, z4, z4, z4};
      f32x4 accB[4] = {z4, z4, z4, z4};
      f32x4 accC[4] = {z4, z4, z4, z4};
      #pragma unroll
      for (int ss = 0; ss < 4; ++ss) {
        uint4v q0 = *(const uint4v*)(hp + (ss << 5));
        uint4v q1 = *(const uint4v*)(hp + (ss << 5) + 4);
        bf16x8 aH = mergelo(q0, q1);
        bf16x8 aL = mergehi(q0, q1);
        #pragma unroll
        for (int j = 0; j < 4; ++j) {
          accA[j] = MFMA(aH, wHi[j][ss], accA[j], 0, 0, 0);
          accB[j] = MFMA(aH, wLo[j][ss], accB[j], 0, 0, 0);
          accC[j] = MFMA(aL, wHi[j][ss], accC[j], 0, 0, 0);
        }
      }
      #pragma unroll
      for (int j = 0; j < 4; ++j) {
        f32x4 s = (accA[j] + accB[j]) + accC[j];
        #pragma unroll
        for (int i = 0; i < 4; ++i)
          red[wv][((aq << 2) + i) * 68 + (j << 4) + am] = s[i];
      }
      __syncthreads();

      unsigned* dst = ((role == 0)
            ? ring0 + (size_t)(t & (NR - 1)) * (BB * HH)
            : h1r  + (size_t)(t & 1) * (BB * HH))
          + (b0 + rowE) * HH + n0 + c0;
      float hv[2]; unsigned pk[2];
      #pragma unroll
      for (int k = 0; k < 2; ++k) {
        const int c = c0 + (k << 5);
        float v = pjv[k];
        #pragma unroll
        for (int w = 0; w < 8; ++w) v += red[w][rowE * 68 + c];
        hv[k] = ftanh(v);
        unsigned pw = (unsigned)f2bf(hv[k]);
        pw |= (unsigned)f2bf(hv[k] - bf2f((u16)pw)) << 16;
        pk[k] = pw;
      }
      #pragma unroll
      for (int k = 0; k < 2; ++k)
        __hip_atomic_store(dst + (k << 5), pk[k],
                           __ATOMIC_RELAXED, __HIP_MEMORY_SCOPE_AGENT);
      __syncthreads();   // drains every wave's vmcnt -> stores MALL-visible
      if (tid == 0)
        __hip_atomic_store(flg + (((size_t)gOwn * TT + t) << 4) + idx, 1u,
                           __ATOMIC_RELEASE, __HIP_MEMORY_SCOPE_AGENT);

      // off-critical-path (NT: keep L2 clean so RELEASE's wbl2 is cheap)
      if (role == 1) {
        float* ob = out + (size_t)(b0 + rowE) * (TT * HH) + (size_t)t * HH + n0 + c0;
        __builtin_nontemporal_store(hv[0], ob);
        __builtin_nontemporal_store(hv[1], ob + 32);
      }
      if (t == TT - 1) {
        float* hb = out + (size_t)BB * TT * HH + (size_t)role * (BB * HH)
                  + (b0 + rowE) * HH + n0 + c0;
        __builtin_nontemporal_store(hv[0], hb);
        __builtin_nontemporal_store(hv[1], hb + 32);
      }
    }
  } else {
    // ========================= proj1: pj1 = h0[t] @ Wx1^T + b1 ==========
    float bias[2];
    bias[0] = bx[HH + n0 + c0] + bh[HH + n0 + c0];
    bias[1] = bx[HH + n0 + c0 + 32] + bh[HH + n0 + c0 + 32];
    for (int t = 0; t < TT; ++t) {
      const unsigned* pa = ones;
      if (lane < 2) {                         // l0 output t, my K-eighth
        pa = flg + (((size_t)bg * TT + t) << 4) + (wv << 1) + lane;
      } else if (lane == 8 || lane == 9) {    // pj1 ring overwrite vs l1
        if (t >= NP1) pa = flg + (((size_t)(2 + bg) * TT + (t - NP1)) << 4) + (wv << 1) + (lane - 8);
      }
      spin(pa, 1);
      __builtin_amdgcn_fence(__ATOMIC_ACQUIRE, "agent");

      const unsigned* hp = ring0 + (size_t)(t & (NR - 1)) * (BB * HH)
                         + (b0 + am) * HH + fragoff;
      f32x4 accA[4] = {z4, z4, z4, z4};
      f32x4 accB[4] = {z4, z4, z4, z4};
      f32x4 accC[4] = {z4, z4, z4, z4};
      #pragma unroll
      for (int ss = 0; ss < 4; ++ss) {
        uint4v q0 = *(const uint4v*)(hp + (ss << 5));
        uint4v q1 = *(const uint4v*)(hp + (ss << 5) + 4);
        bf16x8 aH = mergelo(q0, q1);
        bf16x8 aL = mergehi(q0, q1);
        #pragma unroll
        for (int j = 0; j < 4; ++j) {
          accA[j] = MFMA(aH, wHi[j][ss], accA[j], 0, 0, 0);
          accB[j] = MFMA(aH, wLo[j][ss], accB[j], 0, 0, 0);
          accC[j] = MFMA(aL, wHi[j][ss], accC[j], 0, 0, 0);
        }
      }
      #pragma unroll
      for (int j = 0; j < 4; ++j) {
        f32x4 s = (accA[j] + accB[j]) + accC[j];
        #pragma unroll
        for (int i = 0; i < 4; ++i)
          red[wv][((aq << 2) + i) * 68 + (j << 4) + am] = s[i];
      }
      __syncthreads();

      float* dst = pj1 + (size_t)(t & (NP1 - 1)) * (BB * HH)
                 + (b0 + rowE) * HH + n0 + c0;
      #pragma unroll
      for (int k = 0; k < 2; ++k) {
        const int c = c0 + (k << 5);
        float v = bias[k];
        #pragma unroll
        for (int w = 0; w < 8; ++w) v += red[w][rowE * 68 + c];
        __hip_atomic_store((unsigned*)(dst + (k << 5)),
                           __builtin_bit_cast(unsigned, v),
                           __ATOMIC_RELAXED, __HIP_MEMORY_SCOPE_AGENT);
      }
      __syncthreads();
      if (tid == 0)
        __hip_atomic_store(flg + (((size_t)(4 + bg) * TT + t) << 4) + idx, 1u,
                           __ATOMIC_RELEASE, __HIP_MEMORY_SCOPE_AGENT);
    }
  }
}

// Zero what is read before first write (harness poisons ws with 0xAA):
// ring0 slot NR-1 (h0_{-1}=0), h1r slot 1 (h1_{-1}=0), all flags, ones=1.
__global__ void prep(unsigned* ring0, unsigned* h1r, unsigned* flg,
                     unsigned* ones) {
  int i = blockIdx.x * 256 + threadIdx.x;
  if (i < BB * HH) {
    ring0[(size_t)(NR - 1) * (BB * HH) + i] = 0;
    h1r[(size_t)(BB * HH) + i] = 0;
  }
  if (i < 6 * TT * 16) flg[i] = 0;
  if (i == 0) *ones = 1u;
}

extern "C" void kernel_launch(void* const* d_in, const int* in_sizes, int n_in,
                              void* d_out, int out_size, void* d_ws, size_t ws_size,
                              hipStream_t stream) {
  const float* x  = (const float*)d_in[0];
  const float* Wx = (const float*)d_in[1];
  const float* Wh = (const float*)d_in[2];
  const float* bx = (const float*)d_in[3];
  const float* bh = (const float*)d_in[4];
  float* out = (float*)d_out;

  char* ws = (char*)d_ws;
  unsigned* ring0 = (unsigned*)ws;                                   // 4 MiB
  size_t o = (size_t)NR * BB * HH * sizeof(unsigned);
  unsigned* h1r = (unsigned*)(ws + o);                               // 256 KiB
  o += (size_t)2 * BB * HH * sizeof(unsigned);
  float* pj1 = (float*)(ws + o);                                     // 1 MiB
  o += (size_t)NP1 * BB * HH * sizeof(float);
  unsigned* flg = (unsigned*)(ws + o);                               // 384 KiB
  o += (size_t)6 * TT * 16 * sizeof(unsigned);
  unsigned* ones = (unsigned*)(ws + o);                              // 4 B

  prep<<<384, 256, 0, stream>>>(ring0, h1r, flg, ones);
  // prelude: xp = x @ Wx0^T + b -> out (scratch; rewritten by rec-l1 later)
  xgemm<<<1024, 512, 0, stream>>>(x, Wx, bx, bh, out);
  rnn_pipe<<<96, 512, 0, stream>>>(Wx, Wh, bx, bh, out,
                                   ring0, h1r, pj1, flg, ones);
}